// Round 14
// baseline (245.914 us; speedup 1.0000x reference)
//
#include <hip/hip_runtime.h>
#include <hip/hip_bf16.h>
#include <hip/hip_cooperative_groups.h>

namespace cg = cooperative_groups;

#define N_NODES 50000
#define N_EDGES 800000
#define GRID    512
#define BLK     256
#define STRIDE  (GRID*BLK)     // 131072
#define CHUNK   98             // 512*98 = 50176 >= 50000
#define NTILES  782
#define NB_SCAN 196            // fallback path: ceil(50000/256)

typedef __attribute__((ext_vector_type(8))) short short8;
typedef __attribute__((ext_vector_type(16))) float f32x16;

struct Params {
  const float* msg; const float* x; const int* ei; const float* ea;
  const float* Wl; const float* bl; const float* Wr; const float* br;
  const float* We; const float* att; const float* bias;
  const float* Wfc; const float* bfc;
  float4* rec; float* nodeF;
  __hip_bfloat16* me_hi; __hip_bfloat16* me_lo;
  int* cnt; float* colsum; int* offs; int* cursor; int* bsum;
  float* dout;
};

// ================= shared MFMA tile body (R7 champion + ku-major swizzle) ==
// PASS 0: colsum accumulate into LDS colacc; PASS 1: normalize + coalesced
// store via LDS transpose (xp stride 68 floats = 16B aligned, 2-way banks).
// Swizzle: slot = ku*64 + (col^ku) — stage write spreads banks (free),
// mfma read = permutation of one contiguous 512B window (conflict-free;
// verified numerically + 9x conflict cut in R10/R13).
template<int PASS>
__device__ __forceinline__ void mfma_tile(const Params& P, int tile, char* SMEM)
{
  short8* Bt = (short8*)SMEM;                       // 32 KB
  float* colacc = (float*)(SMEM + 32768);           // PASS0: 4 KB
  float* xp     = (float*)(SMEM + 32768);           // PASS1: 64*68*4 = 17408 B
  float* rcol   = (float*)(SMEM + 50176);           // PASS1: 2 KB

  const int tid = threadIdx.x;
  const int l = tid & 63, w = tid >> 6;
  const int rt = w >> 1, ct = w & 1;
  const int lrow = l & 31, lhalf = l >> 5;
  const int m0 = tile * 64;
  const int row = m0 + rt * 32 + lrow;

  // A fragments from nodeF (h computed on the fly, split bf16 hi/lo)
  float c0a = 0.f, c0b = 0.f, c0d = 0.f, c1a = 0.f, c1b = 0.f, c1d = 0.f;
  bool live = row < N_NODES;
  if (live) {
    const float* nf = P.nodeF + (size_t)row * 8;
    float D0 = nf[0], A00 = nf[1], A10 = nf[2];
    float D1 = nf[3], A01 = nf[4], A11 = nf[5];
    float r0 = 1.0f / (D0 + 1e-16f), r1 = 1.0f / (D1 + 1e-16f);
    c0a = A00 * r0; c0b = A10 * r0; c0d = D0 * r0;
    c1a = A01 * r1; c1b = A11 * r1; c1d = D1 * r1;
  }
  short8 a_hi[8], a_lo[8];
  #pragma unroll
  for (int ks = 0; ks < 8; ++ks) {
    int k0 = ks * 16 + lhalf * 8;
    float ca = (ks < 4) ? c0a : c1a;
    float cbv = (ks < 4) ? c0b : c1b;
    float cd = (ks < 4) ? c0d : c1d;
    float wA[8], wB[8], wC[8], wD[8];
    *(float4*)&wA[0] = *(const float4*)(P.Wl + k0);
    *(float4*)&wA[4] = *(const float4*)(P.Wl + k0 + 4);
    *(float4*)&wB[0] = *(const float4*)(P.Wl + 128 + k0);
    *(float4*)&wB[4] = *(const float4*)(P.Wl + 128 + k0 + 4);
    *(float4*)&wC[0] = *(const float4*)(P.bl + k0);
    *(float4*)&wC[4] = *(const float4*)(P.bl + k0 + 4);
    *(float4*)&wD[0] = *(const float4*)(P.bias + k0);
    *(float4*)&wD[4] = *(const float4*)(P.bias + k0 + 4);
    short8 hi8, lo8;
    #pragma unroll
    for (int j = 0; j < 8; ++j) {
      float v = ca * wA[j] + cbv * wB[j] + cd * wC[j] + wD[j];
      v = (live && v > 0.f) ? v : 0.f;
      __hip_bfloat16 hb = __float2bfloat16(v);
      float rem = v - __bfloat162float(hb);
      __hip_bfloat16 lb = __float2bfloat16(rem);
      short hs, ls;
      __builtin_memcpy(&hs, &hb, 2);
      __builtin_memcpy(&ls, &lb, 2);
      hi8[j] = hs; lo8[j] = ls;
    }
    a_hi[ks] = hi8; a_lo[ks] = lo8;
  }

  for (int cb = 0; cb < 8; ++cb) {
    __syncthreads();     // prev cb's Bt/xp reads done
    #pragma unroll
    for (int q = 0; q < 8; ++q) {
      int lin = q * 256 + tid;
      int s = lin & 1023;
      int col = s >> 4, ku = s & 15;
      int slot = ku * 64 + (col ^ ku);          // ku-major swizzle
      size_t gb = ((size_t)(cb * 64 + col) << 7) + ku * 8;
      if (lin < 1024) Bt[slot] = *(const short8*)(P.me_hi + gb);
      else            Bt[1024 + slot] = *(const short8*)(P.me_lo + gb);
    }
    __syncthreads();

    f32x16 acc = {0.f};
    #pragma unroll
    for (int ks = 0; ks < 8; ++ks) {
      int ku = ks * 2 + lhalf;
      int colB = ct * 32 + lrow;
      int slot = ku * 64 + (colB ^ ku);         // ku-major swizzle
      short8 bh = Bt[slot];
      short8 blo = Bt[1024 + slot];
      acc = __builtin_amdgcn_mfma_f32_32x32x16_bf16(a_hi[ks], bh, acc, 0, 0, 0);
      acc = __builtin_amdgcn_mfma_f32_32x32x16_bf16(a_lo[ks], bh, acc, 0, 0, 0);
      acc = __builtin_amdgcn_mfma_f32_32x32x16_bf16(a_hi[ks], blo, acc, 0, 0, 0);
    }

    if (PASS == 0) {
      float csum = 0.f;
      #pragma unroll
      for (int i = 0; i < 16; ++i) {
        int grow = m0 + rt * 32 + (i & 3) + 8 * (i >> 2) + 4 * lhalf;
        csum += (grow < N_NODES) ? __expf(acc[i]) : 0.f;
      }
      csum += __shfl_xor(csum, 32);
      if (l < 32) colacc[rt * 512 + cb * 64 + ct * 32 + l] += csum;
    } else {
      #pragma unroll
      for (int i = 0; i < 16; ++i) {
        int rl = rt * 32 + (i & 3) + 8 * (i >> 2) + 4 * lhalf;
        xp[rl * 68 + ct * 32 + lrow] = __expf(acc[i]);
      }
      __syncthreads();
      #pragma unroll
      for (int q = 0; q < 4; ++q) {
        int fid = q * 256 + tid;
        int rl = fid >> 4, c4 = fid & 15;
        int grow = m0 + rl;
        float4 v = *(float4*)&xp[rl * 68 + c4 * 4];
        float4 s = *(const float4*)&rcol[cb * 64 + c4 * 4];
        v.x *= s.x; v.y *= s.y; v.z *= s.z; v.w *= s.w;
        if (grow < N_NODES) {
          *(float4*)&P.dout[(size_t)grow * 1024 + cb * 64 + c4 * 4] = v;
          *(float4*)&P.dout[(size_t)grow * 1024 + 512 + cb * 64 + c4 * 4] = v;
        }
      }
    }
  }
}

// ================= cooperative mega-kernel =================
__global__ __launch_bounds__(BLK, 2) void k_all(Params P)
{
  cg::grid_group gg = cg::this_grid();
  __shared__ __align__(16) char SMEM[52224];
  const int b = blockIdx.x, t = threadIdx.x;

  // P0: fc (blocks 0-255, 2 rows each) + zero cnt/colsum (blocks 256-453)
  if (b < 256) {
    float* mrow = (float*)SMEM;
    int r = 2 * b + (t >> 7);
    int col = t & 127;
    mrow[t] = P.msg[r * 128 + col];
    __syncthreads();
    int base = (t >> 7) * 128;
    float acc = P.bfc[col];
    #pragma unroll 8
    for (int k = 0; k < 128; ++k) acc = fmaf(mrow[base + k], P.Wfc[k * 128 + col], acc);
    __hip_bfloat16 hi = __float2bfloat16(acc);
    P.me_hi[r * 128 + col] = hi;
    P.me_lo[r * 128 + col] = __float2bfloat16(acc - __bfloat162float(hi));
  } else if (b < 454) {
    int i = (b - 256) * 256 + t;
    if (i < N_NODES + 512) P.cnt[i] = 0;   // cnt + adjacent colsum
  }
  gg.sync();

  // P1: histogram of dst
  for (int e = b * BLK + t; e < N_EDGES; e += STRIDE)
    atomicAdd(&P.cnt[P.ei[N_EDGES + e]], 1);
  gg.sync();

  // P2: per-chunk local exclusive scan (CHUNK=98, scan width 128)
  {
    int* sh = (int*)SMEM;
    int base = b * CHUNK;
    if (t < 128) sh[t] = 0;
    __syncthreads();
    int v = 0;
    if (t < CHUNK && base + t < N_NODES) { v = P.cnt[base + t]; sh[t] = v; }
    __syncthreads();
    #pragma unroll
    for (int off = 1; off < 128; off <<= 1) {
      int u = (t < 128 && t >= off) ? sh[t - off] : 0;
      __syncthreads();
      if (t < 128) sh[t] += u;
      __syncthreads();
    }
    if (t < CHUNK && base + t < N_NODES) P.offs[base + t] = sh[t] - v;
    if (t == 0) P.bsum[b] = sh[127];
  }
  gg.sync();

  // P3: every block scans the 512 block-sums; add-back + cursor init
  {
    int* eb = (int*)SMEM;                // 512 exclusive values
    int* s3 = eb + 512;                  // 256 partials
    int x0 = P.bsum[2 * t], x1 = P.bsum[2 * t + 1];
    s3[t] = x0 + x1;
    __syncthreads();
    #pragma unroll
    for (int off = 1; off < 256; off <<= 1) {
      int u = (t >= off) ? s3[t - off] : 0;
      __syncthreads();
      s3[t] += u;
      __syncthreads();
    }
    int p = t ? s3[t - 1] : 0;
    eb[2 * t] = p; eb[2 * t + 1] = p + x0;
    __syncthreads();
    int pb = eb[b];
    int base = b * CHUNK;
    if (t < CHUNK && base + t < N_NODES) {
      int o = P.offs[base + t] + pb;
      P.offs[base + t] = o;
      P.cursor[base + t] = o;
    }
    if (b == 0 && t == 0) P.offs[N_NODES] = N_EDGES;
  }
  gg.sync();

  // P4: fused score + scatter
  for (int e = b * BLK + t; e < N_EDGES; e += STRIDE) {
    int s = P.ei[e], d = P.ei[N_EDGES + e];
    float x0s = P.x[2*s], x1s = P.x[2*s+1];
    float x0d = P.x[2*d], x1d = P.x[2*d+1];
    float av = P.ea[e];
    float s0 = 0.f, s1 = 0.f;
    #pragma unroll 8
    for (int k = 0; k < 64; ++k) {
      float m = P.bl[k] + P.br[k];
      m = fmaf(x0s, P.Wl[k], m);
      m = fmaf(x1s, P.Wl[128+k], m);
      m = fmaf(x0d, P.Wr[k], m);
      m = fmaf(x1d, P.Wr[128+k], m);
      m = fmaf(av, P.We[k], m);
      float lk = m > 0.f ? m : 0.2f * m;
      s0 = fmaf(lk, P.att[k], s0);
    }
    #pragma unroll 8
    for (int k = 64; k < 128; ++k) {
      float m = P.bl[k] + P.br[k];
      m = fmaf(x0s, P.Wl[k], m);
      m = fmaf(x1s, P.Wl[128+k], m);
      m = fmaf(x0d, P.Wr[k], m);
      m = fmaf(x1d, P.Wr[128+k], m);
      m = fmaf(av, P.We[k], m);
      float lk = m > 0.f ? m : 0.2f * m;
      s1 = fmaf(lk, P.att[k], s1);
    }
    int pos = atomicAdd(&P.cursor[d], 1);
    P.rec[pos] = make_float4(s0, s1, x0s, x1s);
  }
  gg.sync();

  // P5: per-node gather reduction
  {
    int n = b * BLK + t;
    if (n < N_NODES) {
      int a = P.offs[n], bb = P.offs[n + 1];
      float D0 = 0.f, A00 = 0.f, A10 = 0.f;
      float D1 = 0.f, A01 = 0.f, A11 = 0.f;
      for (int i = a; i < bb; ++i) {
        float4 r = P.rec[i];
        float e0 = __expf(r.x);
        float e1 = __expf(r.y);
        D0 += e0; A00 += e0 * r.z; A10 += e0 * r.w;
        D1 += e1; A01 += e1 * r.z; A11 += e1 * r.w;
      }
      float* nf = P.nodeF + (size_t)n * 8;
      nf[0] = D0; nf[1] = A00; nf[2] = A10;
      nf[3] = D1; nf[4] = A01; nf[5] = A11;
    }
  }
  gg.sync();

  // P6: MFMA colsum pass
  {
    float* colacc = (float*)(SMEM + 32768);
    #pragma unroll
    for (int q = 0; q < 4; ++q) colacc[q * 256 + t] = 0.f;
    __syncthreads();
    for (int tile = b; tile < NTILES; tile += GRID)
      mfma_tile<0>(P, tile, SMEM);
    __syncthreads();
    atomicAdd(&P.colsum[t], colacc[t] + colacc[512 + t]);
    atomicAdd(&P.colsum[t + 256], colacc[256 + t] + colacc[768 + t]);
  }
  gg.sync();

  // P7: MFMA normalize + store pass
  {
    float* rcol = (float*)(SMEM + 50176);
    rcol[t] = 1.0f / P.colsum[t];
    rcol[t + 256] = 1.0f / P.colsum[t + 256];
    __syncthreads();
    for (int tile = b; tile < NTILES; tile += GRID)
      mfma_tile<1>(P, tile, SMEM);
  }
}

// ================= fallback multi-kernel path (proven round-5) =============
__global__ __launch_bounds__(256) void k_zero(int* __restrict__ buf)
{
  int i = blockIdx.x * 256 + threadIdx.x;
  if (i < N_NODES + 512) buf[i] = 0;
}

__global__ __launch_bounds__(256) void k_hist(
    const int* __restrict__ ei, int* __restrict__ cnt)
{
  int e = blockIdx.x * 256 + threadIdx.x;
  if (e >= N_EDGES) return;
  atomicAdd(&cnt[ei[N_EDGES + e]], 1);
}

__global__ __launch_bounds__(256) void k_scan1(
    const int* __restrict__ cnt, int* __restrict__ offs, int* __restrict__ bsum)
{
  __shared__ int sh[256];
  int b = blockIdx.x, t = threadIdx.x;
  int i = b * 256 + t;
  int v = (i < N_NODES) ? cnt[i] : 0;
  sh[t] = v;
  __syncthreads();
  #pragma unroll
  for (int off = 1; off < 256; off <<= 1) {
    int u = (t >= off) ? sh[t - off] : 0;
    __syncthreads();
    sh[t] += u;
    __syncthreads();
  }
  if (i < N_NODES) offs[i] = sh[t] - v;
  if (t == 255) bsum[b] = sh[255];
}

__global__ __launch_bounds__(256) void k_scan2(int* __restrict__ bsum)
{
  __shared__ int sh[256];
  int t = threadIdx.x;
  int v = (t < NB_SCAN) ? bsum[t] : 0;
  sh[t] = v;
  __syncthreads();
  #pragma unroll
  for (int off = 1; off < 256; off <<= 1) {
    int u = (t >= off) ? sh[t - off] : 0;
    __syncthreads();
    sh[t] += u;
    __syncthreads();
  }
  if (t < NB_SCAN) bsum[t] = sh[t] - v;
}

__global__ __launch_bounds__(256) void k_scan3(
    int* __restrict__ offs, const int* __restrict__ bsum, int* __restrict__ cursor)
{
  int b = blockIdx.x, t = threadIdx.x;
  int i = b * 256 + t;
  if (i < N_NODES) {
    int o = offs[i] + bsum[b];
    offs[i] = o;
    cursor[i] = o;
  }
  if (b == 0 && t == 0) offs[N_NODES] = N_EDGES;
}

__global__ __launch_bounds__(256) void k_scatter(Params P)
{
  int e = blockIdx.x * 256 + threadIdx.x;
  if (e >= N_EDGES) return;
  int s = P.ei[e], d = P.ei[N_EDGES + e];
  float x0s = P.x[2*s], x1s = P.x[2*s+1];
  float x0d = P.x[2*d], x1d = P.x[2*d+1];
  float av = P.ea[e];
  float s0 = 0.f, s1 = 0.f;
  #pragma unroll 8
  for (int k = 0; k < 64; ++k) {
    float m = P.bl[k] + P.br[k];
    m = fmaf(x0s, P.Wl[k], m);
    m = fmaf(x1s, P.Wl[128+k], m);
    m = fmaf(x0d, P.Wr[k], m);
    m = fmaf(x1d, P.Wr[128+k], m);
    m = fmaf(av, P.We[k], m);
    float lk = m > 0.f ? m : 0.2f * m;
    s0 = fmaf(lk, P.att[k], s0);
  }
  #pragma unroll 8
  for (int k = 64; k < 128; ++k) {
    float m = P.bl[k] + P.br[k];
    m = fmaf(x0s, P.Wl[k], m);
    m = fmaf(x1s, P.Wl[128+k], m);
    m = fmaf(x0d, P.Wr[k], m);
    m = fmaf(x1d, P.Wr[128+k], m);
    m = fmaf(av, P.We[k], m);
    float lk = m > 0.f ? m : 0.2f * m;
    s1 = fmaf(lk, P.att[k], s1);
  }
  int pos = atomicAdd(&P.cursor[d], 1);
  P.rec[pos] = make_float4(s0, s1, x0s, x1s);
}

__global__ __launch_bounds__(256) void k_gather(Params P)
{
  int n = blockIdx.x * 256 + threadIdx.x;
  if (n >= N_NODES) return;
  int a = P.offs[n], b = P.offs[n + 1];
  float D0 = 0.f, A00 = 0.f, A10 = 0.f;
  float D1 = 0.f, A01 = 0.f, A11 = 0.f;
  for (int i = a; i < b; ++i) {
    float4 r = P.rec[i];
    float e0 = __expf(r.x);
    float e1 = __expf(r.y);
    D0 += e0; A00 += e0 * r.z; A10 += e0 * r.w;
    D1 += e1; A01 += e1 * r.z; A11 += e1 * r.w;
  }
  float* nf = P.nodeF + (size_t)n * 8;
  nf[0] = D0; nf[1] = A00; nf[2] = A10;
  nf[3] = D1; nf[4] = A01; nf[5] = A11;
}

__global__ __launch_bounds__(128) void k_fc(Params P)
{
  int j = blockIdx.x, k = threadIdx.x;
  __shared__ float mrow[128];
  mrow[k] = P.msg[j*128 + k];
  __syncthreads();
  float acc = P.bfc[k];
  #pragma unroll 8
  for (int t = 0; t < 128; ++t) acc = fmaf(mrow[t], P.Wfc[t*128 + k], acc);
  __hip_bfloat16 hi = __float2bfloat16(acc);
  P.me_hi[j*128 + k] = hi;
  P.me_lo[j*128 + k] = __float2bfloat16(acc - __bfloat162float(hi));
}

template<int PASS>
__global__ __launch_bounds__(256, 2) void k_mfma(Params P)
{
  __shared__ __align__(16) char SMEM[52224];
  int tid = threadIdx.x;
  if (PASS == 0) {
    float* colacc = (float*)(SMEM + 32768);
    #pragma unroll
    for (int q = 0; q < 4; ++q) colacc[q * 256 + tid] = 0.f;
    __syncthreads();
    mfma_tile<0>(P, blockIdx.x, SMEM);
    __syncthreads();
    atomicAdd(&P.colsum[tid], colacc[tid] + colacc[512 + tid]);
    atomicAdd(&P.colsum[tid + 256], colacc[256 + tid] + colacc[768 + tid]);
  } else {
    float* rcol = (float*)(SMEM + 50176);
    rcol[tid] = 1.0f / P.colsum[tid];
    rcol[tid + 256] = 1.0f / P.colsum[tid + 256];
    __syncthreads();
    mfma_tile<1>(P, blockIdx.x, SMEM);
  }
}

extern "C" void kernel_launch(void* const* d_in, const int* in_sizes, int n_in,
                              void* d_out, int out_size, void* d_ws, size_t ws_size,
                              hipStream_t stream)
{
  Params P;
  P.msg = (const float*)d_in[0];
  P.x   = (const float*)d_in[1];
  P.ei  = (const int*)d_in[2];
  P.ea  = (const float*)d_in[3];
  // conv1 params (d_in[4..10]) are dead code in the reference
  P.Wl   = (const float*)d_in[11];
  P.bl   = (const float*)d_in[12];
  P.Wr   = (const float*)d_in[13];
  P.br   = (const float*)d_in[14];
  P.We   = (const float*)d_in[15];
  P.att  = (const float*)d_in[16];
  P.bias = (const float*)d_in[17];
  P.Wfc  = (const float*)d_in[18];
  P.bfc  = (const float*)d_in[19];

  char* p = (char*)d_ws;
  P.rec = (float4*)p;                    p += (size_t)N_EDGES * 16;
  P.nodeF = (float*)p;                   p += (size_t)N_NODES * 8 * 4;
  P.me_hi = (__hip_bfloat16*)p;          p += 512 * 128 * 2;
  P.me_lo = (__hip_bfloat16*)p;          p += 512 * 128 * 2;
  P.cnt = (int*)p;                       p += (size_t)N_NODES * 4;   // colsum adjacent
  P.colsum = (float*)p;                  p += 512 * 4;
  P.offs = (int*)p;                      p += (size_t)(N_NODES + 1) * 4;
  P.cursor = (int*)p;                    p += (size_t)N_NODES * 4;
  P.bsum = (int*)p;                      p += GRID * 4;
  P.dout = (float*)d_out;

  // occupancy-gated cooperative launch, multi-kernel fallback
  int maxBlk = 0;
  hipError_t qerr = hipOccupancyMaxActiveBlocksPerMultiprocessor(&maxBlk, k_all, BLK, 0);
  if (qerr == hipSuccess && maxBlk >= 2) {
    void* args[] = { &P };
    hipError_t lerr = hipLaunchCooperativeKernel((void*)k_all, dim3(GRID), dim3(BLK),
                                                 args, 0, stream);
    if (lerr == hipSuccess) return;
  }

  // ---- fallback: proven multi-kernel pipeline ----
  k_zero<<<(N_NODES + 512 + 255) / 256, 256, 0, stream>>>(P.cnt);
  k_hist<<<(N_EDGES + 255) / 256, 256, 0, stream>>>(P.ei, P.cnt);
  k_scan1<<<NB_SCAN, 256, 0, stream>>>(P.cnt, P.offs, P.bsum);
  k_scan2<<<1, 256, 0, stream>>>(P.bsum);
  k_scan3<<<NB_SCAN, 256, 0, stream>>>(P.offs, P.bsum, P.cursor);
  k_scatter<<<(N_EDGES + 255) / 256, 256, 0, stream>>>(P);
  k_gather<<<(N_NODES + 255) / 256, 256, 0, stream>>>(P);
  k_fc<<<512, 128, 0, stream>>>(P);
  k_mfma<0><<<NTILES, 256, 0, stream>>>(P);
  k_mfma<1><<<NTILES, 256, 0, stream>>>(P);
}